// Round 14
// baseline (70.381 us; speedup 1.0000x reference)
//
#include <hip/hip_runtime.h>
#include <math.h>

#define F 128
#define HID 32
#define NH 4
#define WTILE 16   // atoms per wave-microtile (wave-private)
#define BTILE 64   // atoms per block-tile (4 waves)
#define ROWB 512   // bytes per fp32 row
#define PJC 4      // crystals per proj block

typedef __attribute__((ext_vector_type(8))) short bf16x8;
typedef __attribute__((ext_vector_type(4))) float f32x4;

__device__ __forceinline__ float silu_f(float x) {
    return x / (1.0f + __expf(-x));
}

__device__ __forceinline__ uint f2bf(float f) {  // RNE float->bf16 (one-time W1 prep)
    union { float f; uint u; } v; v.f = f;
    uint r = v.u + 0x7fffu + ((v.u >> 16) & 1u);
    return r >> 16;
}

__device__ __forceinline__ uint cvtpk_bf16(float lo, float hi) {  // HW RNE pack
    uint r;
    asm("v_cvt_pk_bf16_f32 %0, %1, %2" : "=v"(r) : "v"(lo), "v"(hi));
    return r;
}

__device__ __forceinline__ void gload_lds16(const void* g, void* l) {
    // async 16B global->LDS; LDS dest = wave-uniform base + lane*16
    __builtin_amdgcn_global_load_lds(
        (const __attribute__((address_space(1))) void*)g,
        (__attribute__((address_space(3))) void*)l, 16, 0, 0);
}

// Scatter segment boundaries: starts[b] = first atom index with seg_id >= b.
__global__ void seg_starts_kernel(const int* __restrict__ seg, int* __restrict__ starts,
                                  int N, int B) {
    int i = blockIdx.x * blockDim.x + threadIdx.x;
    if (i >= N) return;
    int id = seg[i];
    if (i == 0) {
        for (int b = 0; b <= id; ++b) starts[b] = 0;
    } else {
        int prev = seg[i - 1];
        for (int b = prev + 1; b <= id; ++b) starts[b] = i;
    }
    if (i == N - 1) {
        for (int b = id + 1; b <= B; ++b) starts[b] = N;
    }
}

// One block (4 waves) per crystal; waves FULLY AUTONOMOUS in the main loop
// (zero barriers). Wave wv owns atoms [base+16wv, base+16wv+16) of each
// 64-atom block-tile, staged by ITS OWN gload_lds DMA into ITS OWN double
// buffer (vmcnt is per-wave). MFMA gives all 32 hids for its 16 atoms; after
// two shfl_xor reduces every lane holds all 4 head logits -> private
// defer-max softmax (m_/s_ per head in regs) + wave-private sTW + private
// weighted accumulate. One __syncthreads at crystal end merges the 4 waves'
// (m, s, acc) with max-alignment.
__global__ __launch_bounds__(256, 2) void fused11_kernel(
    const float* __restrict__ atom_fea, const int* __restrict__ starts,
    const float* __restrict__ W1, const float* __restrict__ b1,
    const float* __restrict__ W2, const float* __restrict__ b2,
    float* __restrict__ gWacc) {
    __shared__ float sBuf[NH][2][WTILE * F];  // 64 KB: [wave][dbuf][16 rows x 128]
    __shared__ float sTW[NH][WTILE * NH];     // 1 KB: [wave][atom*4+head]

    const int t = threadIdx.x;
    const int b = blockIdx.x;
    const int start = starts[b];
    const int end = starts[b + 1];
    const int wv = t >> 6;
    const int lane = t & 63;
    const int lg = lane >> 4;
    const int l15 = lane & 15;
    const int ch = lane & 3;    // accumulate: head
    const int co = lane >> 2;   // accumulate: feat-oct (feats 8co..8co+7)
    const int lrh = lane >> 5;  // DMA: row half (0/1)
    const int lch = lane & 31;  // DMA: 16B chunk in row

    // ---- one-time register preloads (R6-verified W1T fragment layout) ----
    bf16x8 w1f[2][4];  // [h-half][k-step]; lane: h'=l15, k'=lg*8+j
    #pragma unroll
    for (int m0 = 0; m0 < 2; ++m0)
        #pragma unroll
        for (int kk = 0; kk < 4; ++kk) {
            bf16x8 fr;
            #pragma unroll
            for (int j = 0; j < 8; ++j)
                fr[j] = (short)f2bf(W1[(kk * 32 + lg * 8 + j) * HID + m0 * 16 + l15]);
            w1f[m0][kk] = fr;
        }
    float b1r[8], w2r[8][4];  // uniform (SGPR)
    #pragma unroll
    for (int m0 = 0; m0 < 2; ++m0)
        #pragma unroll
        for (int r = 0; r < 4; ++r) {
            const int h = m0 * 16 + lg * 4 + r;
            b1r[m0 * 4 + r] = b1[h];
            #pragma unroll
            for (int j = 0; j < 4; ++j) w2r[m0 * 4 + r][j] = W2[h * NH + j];
        }
    const float b2r0 = b2[0], b2r1 = b2[1], b2r2 = b2[2], b2r3 = b2[3];

    float m0_ = -INFINITY, m1_ = -INFINITY, m2_ = -INFINITY, m3_ = -INFINITY;
    float s0_ = 0.0f, s1_ = 0.0f, s2_ = 0.0f, s3_ = 0.0f;
    float acc8[8] = {0, 0, 0, 0, 0, 0, 0, 0};  // (head ch, feats 8co..+8), wave's atoms

    const int nt = (end > start) ? (end - start + BTILE - 1) / BTILE : 0;
    const char* gb = (const char*)atom_fea;
    char* bufA = (char*)&sBuf[wv][0][0];
    char* bufB = (char*)&sBuf[wv][1][0];

    // ---- prologue: own-slice DMA of tile 0 (no barrier: wave-private) ----
    if (nt > 0) {
        #pragma unroll
        for (int i = 0; i < 8; ++i) {
            const int lr = 2 * i + lrh;
            int ga = start + wv * WTILE + lr; ga = (ga < end) ? ga : end - 1;
            gload_lds16(gb + (size_t)ga * ROWB + ((lch ^ (lr & 7)) << 4), bufA + i * 1024);
        }
    }
    asm volatile("s_waitcnt vmcnt(0)" ::: "memory");

    int pb = 0;
    for (int ti = 0; ti < nt; ++ti) {
        const int base = start + ti * BTILE;
        const int T = min(BTILE, end - base);
        const int Tw = min(T - wv * WTILE, WTILE);  // wave's valid atoms (may be <=0)
        char* bufc = pb ? bufB : bufA;

        // ---- issue own-slice DMA of tile k+1 (in flight across whole tile) ----
        if (ti + 1 < nt) {
            char* bufn = pb ? bufA : bufB;
            const int nb = base + BTILE;
            #pragma unroll
            for (int i = 0; i < 8; ++i) {
                const int lr = 2 * i + lrh;
                int ga = nb + wv * WTILE + lr; ga = (ga < end) ? ga : end - 1;
                gload_lds16(gb + (size_t)ga * ROWB + ((lch ^ (lr & 7)) << 4), bufn + i * 1024);
            }
        }

        if (Tw > 0) {
            // ---- MFMA MLP: all 32 hids x 16 atoms in this wave ----
            f32x4 a0, a1;
            #pragma unroll
            for (int r = 0; r < 4; ++r) { a0[r] = b1r[r]; a1[r] = b1r[4 + r]; }
            const char* rb = bufc + l15 * ROWB;
            const int rs = l15 & 7;
            #pragma unroll
            for (int kk = 0; kk < 4; ++kk) {
                const int c0 = kk * 8 + lg * 2;
                const float4 va = *(const float4*)(rb + ((c0 ^ rs) << 4));
                const float4 vb = *(const float4*)(rb + (((c0 + 1) ^ rs) << 4));
                union { bf16x8 v; uint u[4]; } fr;
                fr.u[0] = cvtpk_bf16(va.x, va.y);
                fr.u[1] = cvtpk_bf16(va.z, va.w);
                fr.u[2] = cvtpk_bf16(vb.x, vb.y);
                fr.u[3] = cvtpk_bf16(vb.z, vb.w);
                a0 = __builtin_amdgcn_mfma_f32_16x16x32_bf16(w1f[0][kk], fr.v, a0, 0, 0, 0);
                a1 = __builtin_amdgcn_mfma_f32_16x16x32_bf16(w1f[1][kk], fr.v, a1, 0, 0, 0);
            }
            // silu + W2; reduce over lg groups -> every lane: all 4 head logits
            float p0 = 0, p1 = 0, p2 = 0, p3 = 0;
            #pragma unroll
            for (int r = 0; r < 4; ++r) {
                const float sa = silu_f(a0[r]);
                const float sb = silu_f(a1[r]);
                p0 = fmaf(sa, w2r[r][0], fmaf(sb, w2r[4 + r][0], p0));
                p1 = fmaf(sa, w2r[r][1], fmaf(sb, w2r[4 + r][1], p1));
                p2 = fmaf(sa, w2r[r][2], fmaf(sb, w2r[4 + r][2], p2));
                p3 = fmaf(sa, w2r[r][3], fmaf(sb, w2r[4 + r][3], p3));
            }
            p0 += __shfl_xor(p0, 16); p0 += __shfl_xor(p0, 32);
            p1 += __shfl_xor(p1, 16); p1 += __shfl_xor(p1, 32);
            p2 += __shfl_xor(p2, 16); p2 += __shfl_xor(p2, 32);
            p3 += __shfl_xor(p3, 16); p3 += __shfl_xor(p3, 32);
            const bool valid = (l15 < Tw);
            const float v0 = valid ? p0 + b2r0 : -INFINITY;
            const float v1 = valid ? p1 + b2r1 : -INFINITY;
            const float v2 = valid ? p2 + b2r2 : -INFINITY;
            const float v3 = valid ? p3 + b2r3 : -INFINITY;

            // ---- defer-max (T13), private per wave ----
            const float dm = fmaxf(fmaxf(v0 - m0_, v1 - m1_), fmaxf(v2 - m2_, v3 - m3_));
            if (__any(dm > 8.0f)) {  // first tile + rare growth
                float t0 = v0, t1 = v1, t2 = v2, t3 = v3;
                #pragma unroll
                for (int d = 1; d < 16; d <<= 1) {
                    t0 = fmaxf(t0, __shfl_xor(t0, d));
                    t1 = fmaxf(t1, __shfl_xor(t1, d));
                    t2 = fmaxf(t2, __shfl_xor(t2, d));
                    t3 = fmaxf(t3, __shfl_xor(t3, d));
                }
                const float n0 = fmaxf(m0_, t0), n1 = fmaxf(m1_, t1);
                const float n2 = fmaxf(m2_, t2), n3 = fmaxf(m3_, t3);
                const float r0 = __expf(m0_ - n0), r1 = __expf(m1_ - n1);
                const float r2 = __expf(m2_ - n2), r3 = __expf(m3_ - n3);
                s0_ *= r0; s1_ *= r1; s2_ *= r2; s3_ *= r3;
                m0_ = n0; m1_ = n1; m2_ = n2; m3_ = n3;
                const float rsel = (ch & 1) ? ((ch & 2) ? r3 : r1)
                                            : ((ch & 2) ? r2 : r0);
                #pragma unroll
                for (int j = 0; j < 8; ++j) acc8[j] *= rsel;
            }
            const float e0 = valid ? __expf(v0 - m0_) : 0.0f;  // bounded by e^8
            const float e1 = valid ? __expf(v1 - m1_) : 0.0f;
            const float e2 = valid ? __expf(v2 - m2_) : 0.0f;
            const float e3 = valid ? __expf(v3 - m3_) : 0.0f;
            s0_ += e0; s1_ += e1; s2_ += e2; s3_ += e3;  // 4x-replicated over lg; /4 at end
            if (lane < 16) *(float4*)&sTW[wv][lane * NH] = make_float4(e0, e1, e2, e3);

            // ---- weighted accumulate (wave-private; sTW same-wave RAW) ----
            #pragma unroll 8
            for (int a = 0; a < WTILE; ++a) {
                const float w = sTW[wv][a * NH + ch];  // invalid atoms hold 0
                const int sw = a & 7;
                const char* ra = bufc + a * ROWB;
                const float4 q0 = *(const float4*)(ra + (((2 * co) ^ sw) << 4));
                const float4 q1 = *(const float4*)(ra + (((2 * co + 1) ^ sw) << 4));
                acc8[0] = fmaf(w, q0.x, acc8[0]);
                acc8[1] = fmaf(w, q0.y, acc8[1]);
                acc8[2] = fmaf(w, q0.z, acc8[2]);
                acc8[3] = fmaf(w, q0.w, acc8[3]);
                acc8[4] = fmaf(w, q1.x, acc8[4]);
                acc8[5] = fmaf(w, q1.y, acc8[5]);
                acc8[6] = fmaf(w, q1.z, acc8[6]);
                acc8[7] = fmaf(w, q1.w, acc8[7]);
            }
        }
        asm volatile("s_waitcnt vmcnt(0)" ::: "memory");  // own next-tile DMA landed
        pb ^= 1;
    }

    // ---- epilogue: merge 4 autonomous waves (single barrier) ----
    #pragma unroll
    for (int d = 1; d < 64; d <<= 1) {
        s0_ += __shfl_xor(s0_, d); s1_ += __shfl_xor(s1_, d);
        s2_ += __shfl_xor(s2_, d); s3_ += __shfl_xor(s3_, d);
    }
    float* epi = &sBuf[wv][0][0];  // own buffer, free now (no DMA outstanding)
    *(float4*)&epi[lane * 8] = make_float4(acc8[0], acc8[1], acc8[2], acc8[3]);
    *(float4*)&epi[lane * 8 + 4] = make_float4(acc8[4], acc8[5], acc8[6], acc8[7]);
    if (lane == 0) {
        epi[512] = m0_; epi[513] = m1_; epi[514] = m2_; epi[515] = m3_;
        epi[516] = s0_ * 0.25f; epi[517] = s1_ * 0.25f;  // undo 4x lg replication
        epi[518] = s2_ * 0.25f; epi[519] = s3_ * 0.25f;
    }
    __syncthreads();
    if (t < 64) {
        const int ch2 = t & 3, co2 = t >> 2;
        float mw[NH], fw[NH];
        float mg = -INFINITY;
        #pragma unroll
        for (int w = 0; w < NH; ++w) {
            mw[w] = sBuf[w][0][512 + ch2];
            mg = fmaxf(mg, mw[w]);
        }
        float sg = 0.0f;
        #pragma unroll
        for (int w = 0; w < NH; ++w) {
            fw[w] = (mw[w] == -INFINITY) ? 0.0f : __expf(mw[w] - mg);
            sg += sBuf[w][0][516 + ch2] * fw[w];
        }
        const float inv = (sg > 0.0f) ? 1.0f / sg : 0.0f;
        float o[8] = {0, 0, 0, 0, 0, 0, 0, 0};
        #pragma unroll
        for (int w = 0; w < NH; ++w) {
            const float* ap = &sBuf[w][0][t * 8];
            #pragma unroll
            for (int j = 0; j < 8; ++j) o[j] = fmaf(ap[j], fw[w], o[j]);
        }
        float* dst = &gWacc[(size_t)b * 512 + ch2 * F + co2 * 8];
        *(float4*)dst = make_float4(o[0] * inv, o[1] * inv, o[2] * inv, o[3] * inv);
        *(float4*)(dst + 4) = make_float4(o[4] * inv, o[5] * inv, o[6] * inv, o[7] * inv);
    }
}

// K4: out[b] = silu(Wacc[b] @ Wp + bp). PJC crystals per block; 8-deep Wp
// load batching.
__global__ __launch_bounds__(256) void proj_kernel(
    const float* __restrict__ gWacc, const float* __restrict__ Wp,
    const float* __restrict__ bp, float* __restrict__ out, int B) {
    __shared__ float sW[PJC * 512];
    __shared__ float sP[256 * PJC];
    const int t = threadIdx.x;
    const int c0 = blockIdx.x * PJC;
    for (int q = t; q < PJC * 512; q += 256) {
        const int cr = c0 + (q >> 9);
        sW[q] = (cr < B) ? gWacc[(size_t)cr * 512 + (q & 511)] : 0.0f;
    }
    __syncthreads();
    const int f = t & 127, half = t >> 7;
    float acc[PJC] = {};
    const float* wp = Wp + (size_t)(half * 256) * F + f;
    for (int k0 = 0; k0 < 256; k0 += 8) {
        float wpv[8];
        #pragma unroll
        for (int u = 0; u < 8; ++u) wpv[u] = wp[(size_t)(k0 + u) * F];
        #pragma unroll
        for (int u = 0; u < 8; ++u) {
            const int ks = half * 256 + k0 + u;
            #pragma unroll
            for (int g = 0; g < PJC; ++g) acc[g] = fmaf(sW[g * 512 + ks], wpv[u], acc[g]);
        }
    }
    #pragma unroll
    for (int g = 0; g < PJC; ++g) sP[t * PJC + g] = acc[g];
    __syncthreads();
    if (t < 128) {
        const float bpf = bp[t];
        #pragma unroll
        for (int g = 0; g < PJC; ++g) {
            const int cr = c0 + g;
            if (cr < B)
                out[(size_t)cr * F + t] =
                    silu_f(sP[t * PJC + g] + sP[(t + 128) * PJC + g] + bpf);
        }
    }
}

extern "C" void kernel_launch(void* const* d_in, const int* in_sizes, int n_in,
                              void* d_out, int out_size, void* d_ws, size_t ws_size,
                              hipStream_t stream) {
    const float* atom_fea = (const float*)d_in[0];
    const int* seg = (const int*)d_in[1];
    const float* W1 = (const float*)d_in[3];
    const float* b1 = (const float*)d_in[4];
    const float* W2 = (const float*)d_in[5];
    const float* b2 = (const float*)d_in[6];
    const float* Wp = (const float*)d_in[7];
    const float* bp = (const float*)d_in[8];
    float* out = (float*)d_out;

    const int N = in_sizes[0] / F;
    const int B = out_size / F;

    // ws layout: starts[B+1] | Wacc[B*512]
    char* ws = (char*)d_ws;
    int* starts = (int*)ws;
    size_t off = (((size_t)(B + 1) * sizeof(int)) + 255) & ~(size_t)255;
    float* gWacc = (float*)(ws + off);

    seg_starts_kernel<<<(N + 255) / 256, 256, 0, stream>>>(seg, starts, N, B);
    fused11_kernel<<<B, 256, 0, stream>>>(atom_fea, starts, W1, b1, W2, b2, gWacc);
    proj_kernel<<<(B + PJC - 1) / PJC, 256, 0, stream>>>(gWacc, Wp, bp, out, B);
}